// Round 2
// baseline (314.928 us; speedup 1.0000x reference)
//
#include <hip/hip_runtime.h>
#include <math.h>

#define NB 512
#define NATOM 32
#define NE 64
#define NK 32
#define NL0 64
#define NL1 16
#define NSG 80
#define FGAMMA 10.0f
#define FRMAX 5.0f

// centers[k] = RMAX * k / (K-1)
#define CSTEP (FRMAX / (float)(NK - 1))

__device__ __forceinline__ float sigm(float x) { return 1.0f / (1.0f + __expf(-x)); }

// 32-term dot of wave-uniform g (8x float4) with per-lane register weights
__device__ __forceinline__ float dot32(const float4* g, const float* w) {
    float a0 = 0.f, a1 = 0.f, a2 = 0.f, a3 = 0.f;
#pragma unroll
    for (int i = 0; i < 8; i++) {
        float4 gg = g[i];
        a0 = fmaf(gg.x, w[4 * i + 0], a0);
        a1 = fmaf(gg.y, w[4 * i + 1], a1);
        a2 = fmaf(gg.z, w[4 * i + 2], a2);
        a3 = fmaf(gg.w, w[4 * i + 3], a3);
    }
    return (a0 + a1) + (a2 + a3);
}

// ---------------- layer 1 ----------------
// grid (512, 8), block 256.  wave w handles atom a = blockIdx.y*4 + w, lane = channel c in [0,64)
__global__ __launch_bounds__(256) void layer1_kernel(
    const int* __restrict__ Z, const float* __restrict__ geometry,
    const float* __restrict__ mask, const float* __restrict__ emb,
    const float* __restrict__ Wr_ss1, const float* __restrict__ Wmix_ss1,
    const float* __restrict__ Wr_sv1, const float* __restrict__ Wmix_sv1,
    float* __restrict__ s_ws, float* __restrict__ v_ws)
{
    __shared__ __align__(16) float s1[NATOM][NE];      // 8 KB  scaled input scalars
    __shared__ __align__(16) float Gl[4][NATOM][NK];   // 16 KB RBF rows for this chunk's 4 atoms
    __shared__ __align__(16) float rh4[4][NATOM][4];   // 2 KB  {rhat.x,y,z, radii}
    __shared__ __align__(16) float epi[4][NE][4];      // 4 KB  {acc_s, h0, h1, h2}
    __shared__ float geo[NATOM][3];
    __shared__ float ml[NATOM];
    __shared__ int   zl[NATOM];

    const int b    = blockIdx.x;
    const int a0   = blockIdx.y * 4;
    const int tid  = threadIdx.x;
    const int wave = tid >> 6;
    const int lane = tid & 63;

    if (tid < 96)                 geo[tid / 3][tid % 3] = geometry[b * 96 + tid];
    if (tid >= 128 && tid < 160)  ml[tid - 128] = mask[b * NATOM + (tid - 128)];
    if (tid >= 192 && tid < 224)  zl[tid - 192] = Z[b * NATOM + (tid - 192)];
    __syncthreads();

    float msum = 0.f;
#pragma unroll
    for (int n = 0; n < NATOM; n++) msum += ml[n];
    const float scale = 1.0f / sqrtf(msum);

    // s1 = emb[Z] * scale
    for (int idx = tid; idx < NATOM * NE; idx += 256) {
        int n = idx >> 6, c = idx & 63;
        s1[n][c] = emb[zl[n] * NE + c] * scale;
    }
    // pairwise geometry for this chunk
    for (int p = tid; p < 4 * NATOM; p += 256) {
        int ai = p >> 5, n = p & 31;
        int a = a0 + ai;
        float dx = geo[n][0] - geo[a][0];
        float dy = geo[n][1] - geo[a][1];
        float dz = geo[n][2] - geo[a][2];
        float rad = sqrtf(dx * dx + dy * dy + dz * dz + 1e-12f);
        float inv = 1.0f / (rad + 1e-8f);
        rh4[ai][n][0] = dx * inv; rh4[ai][n][1] = dy * inv;
        rh4[ai][n][2] = dz * inv; rh4[ai][n][3] = rad;
    }
    __syncthreads();
    // G = rbf(radii) * mask[n]
    for (int idx = tid; idx < 4 * NATOM * NK; idx += 256) {
        int ai = idx >> 10, n = (idx >> 5) & 31, k = idx & 31;
        float d = rh4[ai][n][3] - (float)k * CSTEP;
        Gl[ai][n][k] = __expf(-FGAMMA * d * d) * ml[n];
    }
    // per-lane radial weight columns (registers)
    float wss[NK], wsv[NK];
#pragma unroll
    for (int k = 0; k < NK; k++) {
        wss[k] = Wr_ss1[k * NE + lane];
        wsv[k] = Wr_sv1[k * NE + lane];
    }
    __syncthreads();

    const int a = a0 + wave;
    float accs = 0.f, h0 = 0.f, h1 = 0.f, h2 = 0.f;
#pragma unroll 2
    for (int n = 0; n < NATOM; n++) {
        const float4* gp = reinterpret_cast<const float4*>(&Gl[wave][n][0]);
        float4 gr[8];
#pragma unroll
        for (int i = 0; i < 8; i++) gr[i] = gp[i];
        float s1nc = s1[n][lane];
        float4 rr = *reinterpret_cast<const float4*>(&rh4[wave][n][0]);
        float rss = dot32(gr, wss);
        float rsv = dot32(gr, wsv);
        accs = fmaf(rss, s1nc, accs);
        float t = rsv * s1nc;
        h0 = fmaf(t, rr.x, h0);
        h1 = fmaf(t, rr.y, h1);
        h2 = fmaf(t, rr.z, h2);
    }
    *reinterpret_cast<float4*>(&epi[wave][lane][0]) = make_float4(accs, h0, h1, h2);
    __syncthreads();

    // epilogue: mixes + activations.  lane<64 -> s channel; lane -> (d = lane&15, x = lane>>4) for v
    const int d = lane & 15;
    const int x = lane >> 4;
    const int xe = (x > 2) ? 0 : x;
    const float* wm_s = Wmix_ss1 + lane;
    const float* wm_g = Wmix_ss1 + 64 + d;
    const float* wm_v = Wmix_sv1 + d;
    float so = 0.f, so2 = 0.f, vo = 0.f;
#pragma unroll 4
    for (int c = 0; c < NE; c++) {
        float sp = epi[wave][c][0];
        so  = fmaf(sp, wm_s[c * NSG], so);
        so2 = fmaf(sp, wm_g[c * NSG], so2);
        vo  = fmaf(epi[wave][c][1 + xe], wm_v[c * NL1], vo);
    }
    const float mla = ml[a];
    // s = silu(s_out[:64]) * mask
    s_ws[(b * NATOM + a) * NE + lane] = so * sigm(so) * mla;
    // v = v_out * sigmoid(gate[d]) * mask
    if (lane < 48) {
        v_ws[(b * NATOM + a) * 48 + d * 3 + x] = vo * sigm(so2) * mla;
    }
}

// ---------------- layer 2 ----------------
// same decomposition; lane plays two roles:
//   role A: c = lane in [0,64)  (ss2 + sv2 paths)
//   role B: (c16 = lane&15, slot = lane>>4); slot<3 -> vv2 component x=slot, slot==3 -> vs2
__global__ __launch_bounds__(256) void layer2_kernel(
    const float* __restrict__ geometry, const float* __restrict__ mask,
    const float* __restrict__ Wr_ss2, const float* __restrict__ Wmix_ss2,
    const float* __restrict__ Wr_sv2, const float* __restrict__ Wmix_sv2,
    const float* __restrict__ Wr_vv2, const float* __restrict__ Wmix_vv2,
    const float* __restrict__ Wr_vs2, const float* __restrict__ Wmix_vs2,
    const float* __restrict__ s_ws, const float* __restrict__ v_ws,
    float* __restrict__ out)
{
    __shared__ __align__(16) float s2l[NATOM][NE];     // 8 KB
    __shared__ __align__(16) float v2l[NATOM][48];     // 6 KB
    __shared__ __align__(16) float Gl[4][NATOM][NK];   // 16 KB
    __shared__ __align__(16) float rh4[4][NATOM][4];   // 2 KB
    __shared__ __align__(16) float epi[4][NE][4];      // 4 KB
    __shared__ float epiB[4][64];                      // 1 KB
    __shared__ float geo[NATOM][3];
    __shared__ float ml[NATOM];

    const int b    = blockIdx.x;
    const int a0   = blockIdx.y * 4;
    const int tid  = threadIdx.x;
    const int wave = tid >> 6;
    const int lane = tid & 63;

    if (tid < 96)                 geo[tid / 3][tid % 3] = geometry[b * 96 + tid];
    if (tid >= 128 && tid < 160)  ml[tid - 128] = mask[b * NATOM + (tid - 128)];
    __syncthreads();

    float msum = 0.f;
#pragma unroll
    for (int n = 0; n < NATOM; n++) msum += ml[n];
    const float scale = 1.0f / sqrtf(msum);

    for (int idx = tid; idx < NATOM * NE; idx += 256) {
        s2l[idx >> 6][idx & 63] = s_ws[b * (NATOM * NE) + idx] * scale;
    }
    for (int idx = tid; idx < NATOM * 48; idx += 256) {
        v2l[idx / 48][idx % 48] = v_ws[b * (NATOM * 48) + idx] * scale;
    }
    for (int p = tid; p < 4 * NATOM; p += 256) {
        int ai = p >> 5, n = p & 31;
        int a = a0 + ai;
        float dx = geo[n][0] - geo[a][0];
        float dy = geo[n][1] - geo[a][1];
        float dz = geo[n][2] - geo[a][2];
        float rad = sqrtf(dx * dx + dy * dy + dz * dz + 1e-12f);
        float inv = 1.0f / (rad + 1e-8f);
        rh4[ai][n][0] = dx * inv; rh4[ai][n][1] = dy * inv;
        rh4[ai][n][2] = dz * inv; rh4[ai][n][3] = rad;
    }
    __syncthreads();
    for (int idx = tid; idx < 4 * NATOM * NK; idx += 256) {
        int ai = idx >> 10, n = (idx >> 5) & 31, k = idx & 31;
        float d = rh4[ai][n][3] - (float)k * CSTEP;
        Gl[ai][n][k] = __expf(-FGAMMA * d * d) * ml[n];
    }

    const int c16  = lane & 15;
    const int slot = lane >> 4;
    float wss[NK], wsv[NK], wB[NK];
#pragma unroll
    for (int k = 0; k < NK; k++) {
        wss[k] = Wr_ss2[k * NL0 + lane];
        wsv[k] = Wr_sv2[k * NL0 + lane];
        wB[k]  = (slot < 3) ? Wr_vv2[k * NL1 + c16] : Wr_vs2[k * NL1 + c16];
    }
    __syncthreads();

    const int a = a0 + wave;
    float accs = 0.f, h0 = 0.f, h1 = 0.f, h2 = 0.f, accB = 0.f;
#pragma unroll 2
    for (int n = 0; n < NATOM; n++) {
        const float4* gp = reinterpret_cast<const float4*>(&Gl[wave][n][0]);
        float4 gr[8];
#pragma unroll
        for (int i = 0; i < 8; i++) gr[i] = gp[i];
        float s2nc = s2l[n][lane];
        float4 rr = *reinterpret_cast<const float4*>(&rh4[wave][n][0]);
        float rA1 = dot32(gr, wss);
        float rA2 = dot32(gr, wsv);
        float rB  = dot32(gr, wB);
        accs = fmaf(rA1, s2nc, accs);
        float t = rA2 * s2nc;
        h0 = fmaf(t, rr.x, h0);
        h1 = fmaf(t, rr.y, h1);
        h2 = fmaf(t, rr.z, h2);
        float v0 = v2l[n][c16 * 3 + 0];
        float v1 = v2l[n][c16 * 3 + 1];
        float v2 = v2l[n][c16 * 3 + 2];
        float dotrv = fmaf(rr.x, v0, fmaf(rr.y, v1, rr.z * v2));
        float opB = (slot == 0) ? v0 : (slot == 1) ? v1 : (slot == 2) ? v2 : dotrv;
        accB = fmaf(rB, opB, accB);
    }
    *reinterpret_cast<float4*>(&epi[wave][lane][0]) = make_float4(accs, h0, h1, h2);
    epiB[wave][lane] = accB;
    __syncthreads();

    // epilogue: s_out2 = (ss2 path) @ Wmix_ss2 + (vs2 path) @ Wmix_vs2
    //           v_out2 = hv @ Wmix_sv2 + hvv @ Wmix_vv2
    const int d = lane & 15;
    const int x = lane >> 4;
    const int xe = (x > 2) ? 0 : x;
    float so = 0.f, so2 = 0.f, vo = 0.f;
#pragma unroll 4
    for (int c = 0; c < NE; c++) {
        float sp = epi[wave][c][0];
        so  = fmaf(sp, Wmix_ss2[c * NSG + lane], so);
        so2 = fmaf(sp, Wmix_ss2[c * NSG + 64 + d], so2);
        vo  = fmaf(epi[wave][c][1 + xe], Wmix_sv2[c * NL1 + d], vo);
    }
#pragma unroll
    for (int c = 0; c < NL1; c++) {
        float svs = epiB[wave][48 + c];          // vs2 accumulators live in slot==3 lanes
        so  = fmaf(svs, Wmix_vs2[c * NSG + lane], so);
        so2 = fmaf(svs, Wmix_vs2[c * NSG + 64 + d], so2);
        vo  = fmaf(epiB[wave][xe * 16 + c], Wmix_vv2[c * NL1 + d], vo);
    }
    const float mla = ml[a];
    float* orow = out + (b * NATOM + a) * (NL0 + 3 * NL1);
    orow[lane] = so * sigm(so) * mla;            // scalar part, ch 0..63
    if (lane < 48) {
        orow[64 + d * 3 + x] = vo * sigm(so2) * mla;   // vector part, [d][x]
    }
}

extern "C" void kernel_launch(void* const* d_in, const int* in_sizes, int n_in,
                              void* d_out, int out_size, void* d_ws, size_t ws_size,
                              hipStream_t stream)
{
    const int*   Z        = (const int*)  d_in[0];
    const float* geometry = (const float*)d_in[1];
    const float* mask     = (const float*)d_in[2];
    const float* emb      = (const float*)d_in[3];
    const float* Wr_ss1   = (const float*)d_in[4];
    const float* Wmix_ss1 = (const float*)d_in[5];
    const float* Wr_sv1   = (const float*)d_in[6];
    const float* Wmix_sv1 = (const float*)d_in[7];
    const float* Wr_ss2   = (const float*)d_in[8];
    const float* Wmix_ss2 = (const float*)d_in[9];
    const float* Wr_sv2   = (const float*)d_in[10];
    const float* Wmix_sv2 = (const float*)d_in[11];
    const float* Wr_vv2   = (const float*)d_in[12];
    const float* Wmix_vv2 = (const float*)d_in[13];
    const float* Wr_vs2   = (const float*)d_in[14];
    const float* Wmix_vs2 = (const float*)d_in[15];

    float* out  = (float*)d_out;
    float* s_ws = (float*)d_ws;                    // [512][32][64] f32 = 4 MB
    float* v_ws = s_ws + (size_t)NB * NATOM * NE;  // [512][32][48] f32 = 3 MB

    dim3 grid(NB, 8), block(256);
    layer1_kernel<<<grid, block, 0, stream>>>(Z, geometry, mask, emb,
                                              Wr_ss1, Wmix_ss1, Wr_sv1, Wmix_sv1,
                                              s_ws, v_ws);
    layer2_kernel<<<grid, block, 0, stream>>>(geometry, mask,
                                              Wr_ss2, Wmix_ss2, Wr_sv2, Wmix_sv2,
                                              Wr_vv2, Wmix_vv2, Wr_vs2, Wmix_vs2,
                                              s_ws, v_ws, out);
}

// Round 5
// 247.551 us; speedup vs baseline: 1.2722x; 1.2722x over previous
//
#include <hip/hip_runtime.h>
#include <math.h>

#define NB 512
#define NATOM 32
#define NE 64
#define NK 32
#define NL1 16
#define NSG 80
#define CSTEP (5.0f / 31.0f)   // RMAX/(K-1)

typedef __attribute__((ext_vector_type(8)))  short s8v;    // 8 bf16 (4 VGPR) MFMA operand
typedef __attribute__((ext_vector_type(16))) float f16v;   // 32x32 accumulator

__device__ __forceinline__ float sigm(float x) { return 1.0f / (1.0f + __expf(-x)); }

// f32 -> bf16 (RNE) and back
__device__ __forceinline__ short f2bf(float f) {
    unsigned u = __float_as_uint(f);
    unsigned r = (u + 0x7fffu + ((u >> 16) & 1u)) >> 16;
    return (short)r;
}
__device__ __forceinline__ float bf2f(short s) {
    return __uint_as_float(((unsigned)(unsigned short)s) << 16);
}

// ---------------- layer 1 ----------------
// grid (512, 8), block 256. wave w = atom a0+w. MFMA: C[n=32][c=128] = G_a[n][k=32] @ Wcat[k][c]
// 3-term bf16 split: Gh@Wh + Gl@Wh + Gh@Wl.
__global__ __launch_bounds__(256) void layer1_kernel(
    const int* __restrict__ Z, const float* __restrict__ geometry,
    const float* __restrict__ mask, const float* __restrict__ emb,
    const float* __restrict__ Wr_ss1, const float* __restrict__ Wmix_ss1,
    const float* __restrict__ Wr_sv1, const float* __restrict__ Wmix_sv1,
    float* __restrict__ s_ws, float* __restrict__ v_ws)
{
    __shared__ float s1[NATOM][NE];                    // 8 KB
    __shared__ __align__(16) float rh4[4][NATOM][4];   // 2 KB {rhat.xyz, rad}
    __shared__ __align__(16) float epi_s[4][NE];       // 1 KB
    __shared__ __align__(16) float epi_h[4][3][NE];    // 3 KB
    __shared__ float geo[NATOM][3];
    __shared__ float ml[NATOM];
    __shared__ int   zl[NATOM];

    const int b    = blockIdx.x;
    const int a0   = blockIdx.y * 4;
    const int tid  = threadIdx.x;
    const int wave = tid >> 6;
    const int lane = tid & 63;
    const int l31  = lane & 31;
    const int hi   = lane >> 5;

    // ---- B fragments (weights, bf16 hi/lo), same for every wave ----
    // B[k][c] for 32x32x16: lane holds col c = nt*32 + l31, k = ks*16 + hi*8 + j
    s8v Bh[4][2], Bl[4][2];
#pragma unroll
    for (int nt = 0; nt < 4; nt++) {
        const float* src = (nt < 2) ? (Wr_ss1 + nt * 32 + l31)
                                    : (Wr_sv1 + (nt - 2) * 32 + l31);
#pragma unroll
        for (int ks = 0; ks < 2; ks++) {
#pragma unroll
            for (int j = 0; j < 8; j++) {
                int k = ks * 16 + hi * 8 + j;
                float w = src[k * 64];
                short h = f2bf(w);
                Bh[nt][ks][j] = h;
                Bl[nt][ks][j] = f2bf(w - bf2f(h));
            }
        }
    }

    if (tid < 96)                 geo[tid / 3][tid % 3] = geometry[b * 96 + tid];
    if (tid >= 128 && tid < 160)  ml[tid - 128] = mask[b * NATOM + (tid - 128)];
    if (tid >= 192 && tid < 224)  zl[tid - 192] = Z[b * NATOM + (tid - 192)];
    __syncthreads();

    float msum = 0.f;
#pragma unroll
    for (int n = 0; n < NATOM; n++) msum += ml[n];
    const float scale = 1.0f / sqrtf(msum);

    for (int idx = tid; idx < NATOM * NE; idx += 256) {
        s1[idx >> 6][idx & 63] = emb[zl[idx >> 6] * NE + (idx & 63)] * scale;
    }
    for (int p = tid; p < 4 * NATOM; p += 256) {
        int ai = p >> 5, n = p & 31, a = a0 + ai;
        float dx = geo[n][0] - geo[a][0];
        float dy = geo[n][1] - geo[a][1];
        float dz = geo[n][2] - geo[a][2];
        float rad = sqrtf(dx * dx + dy * dy + dz * dz + 1e-12f);
        float inv = 1.0f / (rad + 1e-8f);
        rh4[ai][n][0] = dx * inv; rh4[ai][n][1] = dy * inv;
        rh4[ai][n][2] = dz * inv; rh4[ai][n][3] = rad;
    }
    __syncthreads();

    // ---- A fragments: G row n = l31 of this wave's atom, computed in-register ----
    const float rn  = rh4[wave][l31][3];
    const float mln = ml[l31];
    s8v Ah[2], Al[2];
#pragma unroll
    for (int ks = 0; ks < 2; ks++) {
#pragma unroll
        for (int j = 0; j < 8; j++) {
            float mu = (float)(ks * 16 + hi * 8 + j) * CSTEP;
            float dd = rn - mu;
            float g  = __expf(-10.0f * dd * dd) * mln;
            short h  = f2bf(g);
            Ah[ks][j] = h;
            Al[ks][j] = f2bf(g - bf2f(h));
        }
    }

    // ---- MFMA + per-tile-pair epilogue: pair p covers ss-tile p and sv-tile p+2 ----
#pragma unroll
    for (int p = 0; p < 2; p++) {
        f16v accS = {};
        f16v accV = {};
#pragma unroll
        for (int ks = 0; ks < 2; ks++) {
            accS = __builtin_amdgcn_mfma_f32_32x32x16_bf16(Ah[ks], Bh[p][ks],     accS, 0, 0, 0);
            accS = __builtin_amdgcn_mfma_f32_32x32x16_bf16(Al[ks], Bh[p][ks],     accS, 0, 0, 0);
            accS = __builtin_amdgcn_mfma_f32_32x32x16_bf16(Ah[ks], Bl[p][ks],     accS, 0, 0, 0);
            accV = __builtin_amdgcn_mfma_f32_32x32x16_bf16(Ah[ks], Bh[p + 2][ks], accV, 0, 0, 0);
            accV = __builtin_amdgcn_mfma_f32_32x32x16_bf16(Al[ks], Bh[p + 2][ks], accV, 0, 0, 0);
            accV = __builtin_amdgcn_mfma_f32_32x32x16_bf16(Ah[ks], Bl[p + 2][ks], accV, 0, 0, 0);
        }
        const int c = p * 32 + l31;
        float ps = 0.f, g0 = 0.f, g1 = 0.f, g2 = 0.f;
#pragma unroll
        for (int r = 0; r < 16; r++) {
            int n = (r & 3) + 8 * (r >> 2) + 4 * hi;   // verified C/D row map (m74/m101)
            float sv = s1[n][c];
            ps = fmaf(accS[r], sv, ps);
            float t = accV[r] * sv;
            float4 rr = *reinterpret_cast<const float4*>(&rh4[wave][n][0]);
            g0 = fmaf(t, rr.x, g0);
            g1 = fmaf(t, rr.y, g1);
            g2 = fmaf(t, rr.z, g2);
        }
        ps += __shfl_xor(ps, 32);
        g0 += __shfl_xor(g0, 32);
        g1 += __shfl_xor(g1, 32);
        g2 += __shfl_xor(g2, 32);
        if (hi == 0) {
            epi_s[wave][c]    = ps;
            epi_h[wave][0][c] = g0;
            epi_h[wave][1][c] = g1;
            epi_h[wave][2][c] = g2;
        }
    }

    // ---- mix + activations (per-wave private epi; no barrier needed) ----
    const int d  = lane & 15;
    const int x  = lane >> 4;
    const int xe = (x > 2) ? 0 : x;
    float so = 0.f, so2 = 0.f, vo = 0.f;
    const float4* es4 = reinterpret_cast<const float4*>(&epi_s[wave][0]);
    const float4* eh4 = reinterpret_cast<const float4*>(&epi_h[wave][xe][0]);
#pragma unroll 4
    for (int c4 = 0; c4 < 16; c4++) {
        float4 sp = es4[c4];
        float4 hp = eh4[c4];
#pragma unroll
        for (int u = 0; u < 4; u++) {
            int c = c4 * 4 + u;
            float spv = (&sp.x)[u];
            so  = fmaf(spv, Wmix_ss1[c * NSG + lane], so);
            so2 = fmaf(spv, Wmix_ss1[c * NSG + 64 + d], so2);
            vo  = fmaf((&hp.x)[u], Wmix_sv1[c * NL1 + d], vo);
        }
    }
    const float mla = ml[a0 + wave];
    s_ws[(b * NATOM + a0 + wave) * NE + lane] = so * sigm(so) * mla;
    if (lane < 48) {
        v_ws[(b * NATOM + a0 + wave) * 48 + d * 3 + x] = vo * sigm(so2) * mla;
    }
}

// ---------------- layer 2 ----------------
// 5 N-tiles: 0,1 = ss (c 0..63), 2,3 = sv (c 0..63), 4 = vv (l31<16) | vs (l31>=16)
__global__ __launch_bounds__(256) void layer2_kernel(
    const float* __restrict__ geometry, const float* __restrict__ mask,
    const float* __restrict__ Wr_ss2, const float* __restrict__ Wmix_ss2,
    const float* __restrict__ Wr_sv2, const float* __restrict__ Wmix_sv2,
    const float* __restrict__ Wr_vv2, const float* __restrict__ Wmix_vv2,
    const float* __restrict__ Wr_vs2, const float* __restrict__ Wmix_vs2,
    const float* __restrict__ s_ws, const float* __restrict__ v_ws,
    float* __restrict__ out)
{
    __shared__ float s2[NATOM][NE];                    // 8 KB
    __shared__ float v2[NATOM][48];                    // 6 KB
    __shared__ __align__(16) float rh4[4][NATOM][4];   // 2 KB
    __shared__ float rv[4][NATOM][NL1];                // 8 KB  rv[ai][n][c16] = rhat_ai,n . v2[n][c16]
    __shared__ __align__(16) float epi_s[4][NE];       // 1 KB
    __shared__ __align__(16) float epi_h[4][3][NE];    // 3 KB
    __shared__ __align__(16) float epi_vv[4][3][NL1];  // 0.75 KB
    __shared__ __align__(16) float epi_vs[4][NL1];     // 0.25 KB
    __shared__ float geo[NATOM][3];
    __shared__ float ml[NATOM];

    const int b    = blockIdx.x;
    const int a0   = blockIdx.y * 4;
    const int tid  = threadIdx.x;
    const int wave = tid >> 6;
    const int lane = tid & 63;
    const int l31  = lane & 31;
    const int hi   = lane >> 5;

    // ---- B fragments ----
    s8v Bh[5][2], Bl[5][2];
#pragma unroll
    for (int nt = 0; nt < 5; nt++) {
        const float* src;
        int stride;
        if (nt < 2)      { src = Wr_ss2 + nt * 32 + l31;         stride = 64; }
        else if (nt < 4) { src = Wr_sv2 + (nt - 2) * 32 + l31;   stride = 64; }
        else             { src = (l31 < 16) ? (Wr_vv2 + l31) : (Wr_vs2 + (l31 - 16)); stride = 16; }
#pragma unroll
        for (int ks = 0; ks < 2; ks++) {
#pragma unroll
            for (int j = 0; j < 8; j++) {
                int k = ks * 16 + hi * 8 + j;
                float w = src[k * stride];
                short h = f2bf(w);
                Bh[nt][ks][j] = h;
                Bl[nt][ks][j] = f2bf(w - bf2f(h));
            }
        }
    }

    if (tid < 96)                 geo[tid / 3][tid % 3] = geometry[b * 96 + tid];
    if (tid >= 128 && tid < 160)  ml[tid - 128] = mask[b * NATOM + (tid - 128)];
    __syncthreads();

    float msum = 0.f;
#pragma unroll
    for (int n = 0; n < NATOM; n++) msum += ml[n];
    const float scale = 1.0f / sqrtf(msum);

    for (int idx = tid; idx < NATOM * NE; idx += 256) {
        s2[idx >> 6][idx & 63] = s_ws[b * (NATOM * NE) + idx] * scale;
    }
    for (int idx = tid; idx < NATOM * 48; idx += 256) {
        v2[idx / 48][idx % 48] = v_ws[b * (NATOM * 48) + idx] * scale;
    }
    for (int p = tid; p < 4 * NATOM; p += 256) {
        int ai = p >> 5, n = p & 31, a = a0 + ai;
        float dx = geo[n][0] - geo[a][0];
        float dy = geo[n][1] - geo[a][1];
        float dz = geo[n][2] - geo[a][2];
        float rad = sqrtf(dx * dx + dy * dy + dz * dz + 1e-12f);
        float inv = 1.0f / (rad + 1e-8f);
        rh4[ai][n][0] = dx * inv; rh4[ai][n][1] = dy * inv;
        rh4[ai][n][2] = dz * inv; rh4[ai][n][3] = rad;
    }
    __syncthreads();
    // rv[ai][n][c16] = sum_x rhat[ai][n][x] * v2[n][c16][x]
    for (int idx = tid; idx < 4 * NATOM * NL1; idx += 256) {
        int ai = idx >> 9, n = (idx >> 4) & 31, c = idx & 15;
        rv[ai][n][c] = rh4[ai][n][0] * v2[n][c * 3 + 0]
                     + rh4[ai][n][1] * v2[n][c * 3 + 1]
                     + rh4[ai][n][2] * v2[n][c * 3 + 2];
    }
    __syncthreads();

    // ---- A fragments ----
    const float rn  = rh4[wave][l31][3];
    const float mln = ml[l31];
    s8v Ah[2], Al[2];
#pragma unroll
    for (int ks = 0; ks < 2; ks++) {
#pragma unroll
        for (int j = 0; j < 8; j++) {
            float mu = (float)(ks * 16 + hi * 8 + j) * CSTEP;
            float dd = rn - mu;
            float g  = __expf(-10.0f * dd * dd) * mln;
            short h  = f2bf(g);
            Ah[ks][j] = h;
            Al[ks][j] = f2bf(g - bf2f(h));
        }
    }

    // ---- pairs: (0,2) and (1,3) ----
#pragma unroll
    for (int p = 0; p < 2; p++) {
        f16v accS = {};
        f16v accV = {};
#pragma unroll
        for (int ks = 0; ks < 2; ks++) {
            accS = __builtin_amdgcn_mfma_f32_32x32x16_bf16(Ah[ks], Bh[p][ks],     accS, 0, 0, 0);
            accS = __builtin_amdgcn_mfma_f32_32x32x16_bf16(Al[ks], Bh[p][ks],     accS, 0, 0, 0);
            accS = __builtin_amdgcn_mfma_f32_32x32x16_bf16(Ah[ks], Bl[p][ks],     accS, 0, 0, 0);
            accV = __builtin_amdgcn_mfma_f32_32x32x16_bf16(Ah[ks], Bh[p + 2][ks], accV, 0, 0, 0);
            accV = __builtin_amdgcn_mfma_f32_32x32x16_bf16(Al[ks], Bh[p + 2][ks], accV, 0, 0, 0);
            accV = __builtin_amdgcn_mfma_f32_32x32x16_bf16(Ah[ks], Bl[p + 2][ks], accV, 0, 0, 0);
        }
        const int c = p * 32 + l31;
        float ps = 0.f, g0 = 0.f, g1 = 0.f, g2 = 0.f;
#pragma unroll
        for (int r = 0; r < 16; r++) {
            int n = (r & 3) + 8 * (r >> 2) + 4 * hi;
            float sv = s2[n][c];
            ps = fmaf(accS[r], sv, ps);
            float t = accV[r] * sv;
            float4 rr = *reinterpret_cast<const float4*>(&rh4[wave][n][0]);
            g0 = fmaf(t, rr.x, g0);
            g1 = fmaf(t, rr.y, g1);
            g2 = fmaf(t, rr.z, g2);
        }
        ps += __shfl_xor(ps, 32);
        g0 += __shfl_xor(g0, 32);
        g1 += __shfl_xor(g1, 32);
        g2 += __shfl_xor(g2, 32);
        if (hi == 0) {
            epi_s[wave][c]    = ps;
            epi_h[wave][0][c] = g0;
            epi_h[wave][1][c] = g1;
            epi_h[wave][2][c] = g2;
        }
    }

    // ---- tile 4: vv (l31<16) / vs (l31>=16) ----
    {
        f16v acc4 = {};
#pragma unroll
        for (int ks = 0; ks < 2; ks++) {
            acc4 = __builtin_amdgcn_mfma_f32_32x32x16_bf16(Ah[ks], Bh[4][ks], acc4, 0, 0, 0);
            acc4 = __builtin_amdgcn_mfma_f32_32x32x16_bf16(Al[ks], Bh[4][ks], acc4, 0, 0, 0);
            acc4 = __builtin_amdgcn_mfma_f32_32x32x16_bf16(Ah[ks], Bl[4][ks], acc4, 0, 0, 0);
        }
        const int c16 = l31 & 15;
        float hv0 = 0.f, hv1 = 0.f, hv2 = 0.f, svs = 0.f;
#pragma unroll
        for (int r = 0; r < 16; r++) {
            int n = (r & 3) + 8 * (r >> 2) + 4 * hi;
            if (l31 < 16) {
                hv0 = fmaf(acc4[r], v2[n][c16 * 3 + 0], hv0);
                hv1 = fmaf(acc4[r], v2[n][c16 * 3 + 1], hv1);
                hv2 = fmaf(acc4[r], v2[n][c16 * 3 + 2], hv2);
            } else {
                svs = fmaf(acc4[r], rv[wave][n][c16], svs);
            }
        }
        hv0 += __shfl_xor(hv0, 32);
        hv1 += __shfl_xor(hv1, 32);
        hv2 += __shfl_xor(hv2, 32);
        svs += __shfl_xor(svs, 32);
        if (hi == 0) {
            if (l31 < 16) {
                epi_vv[wave][0][c16] = hv0;
                epi_vv[wave][1][c16] = hv1;
                epi_vv[wave][2][c16] = hv2;
            } else {
                epi_vs[wave][c16] = svs;
            }
        }
    }

    // ---- mix + activations ----
    const int d  = lane & 15;
    const int x  = lane >> 4;
    const int xe = (x > 2) ? 0 : x;
    float so = 0.f, so2 = 0.f, vo = 0.f;
    const float4* es4 = reinterpret_cast<const float4*>(&epi_s[wave][0]);
    const float4* eh4 = reinterpret_cast<const float4*>(&epi_h[wave][xe][0]);
#pragma unroll 4
    for (int c4 = 0; c4 < 16; c4++) {
        float4 sp = es4[c4];
        float4 hp = eh4[c4];
#pragma unroll
        for (int u = 0; u < 4; u++) {
            int c = c4 * 4 + u;
            float spv = (&sp.x)[u];
            so  = fmaf(spv, Wmix_ss2[c * NSG + lane], so);
            so2 = fmaf(spv, Wmix_ss2[c * NSG + 64 + d], so2);
            vo  = fmaf((&hp.x)[u], Wmix_sv2[c * NL1 + d], vo);
        }
    }
    const float4* evs4 = reinterpret_cast<const float4*>(&epi_vs[wave][0]);
    const float4* evv4 = reinterpret_cast<const float4*>(&epi_vv[wave][xe][0]);
#pragma unroll
    for (int c4 = 0; c4 < 4; c4++) {
        float4 vs = evs4[c4];
        float4 vv = evv4[c4];
#pragma unroll
        for (int u = 0; u < 4; u++) {
            int c = c4 * 4 + u;
            float vsv = (&vs.x)[u];
            so  = fmaf(vsv, Wmix_vs2[c * NSG + lane], so);
            so2 = fmaf(vsv, Wmix_vs2[c * NSG + 64 + d], so2);
            vo  = fmaf((&vv.x)[u], Wmix_vv2[c * NL1 + d], vo);
        }
    }
    const float mla = ml[a0 + wave];
    float* orow = out + (b * NATOM + a0 + wave) * (NE + 3 * NL1);
    orow[lane] = so * sigm(so) * mla;
    if (lane < 48) {
        orow[64 + d * 3 + x] = vo * sigm(so2) * mla;
    }
}

extern "C" void kernel_launch(void* const* d_in, const int* in_sizes, int n_in,
                              void* d_out, int out_size, void* d_ws, size_t ws_size,
                              hipStream_t stream)
{
    const int*   Z        = (const int*)  d_in[0];
    const float* geometry = (const float*)d_in[1];
    const float* mask     = (const float*)d_in[2];
    const float* emb      = (const float*)d_in[3];
    const float* Wr_ss1   = (const float*)d_in[4];
    const float* Wmix_ss1 = (const float*)d_in[5];
    const float* Wr_sv1   = (const float*)d_in[6];
    const float* Wmix_sv1 = (const float*)d_in[7];
    const float* Wr_ss2   = (const float*)d_in[8];
    const float* Wmix_ss2 = (const float*)d_in[9];
    const float* Wr_sv2   = (const float*)d_in[10];
    const float* Wmix_sv2 = (const float*)d_in[11];
    const float* Wr_vv2   = (const float*)d_in[12];
    const float* Wmix_vv2 = (const float*)d_in[13];
    const float* Wr_vs2   = (const float*)d_in[14];
    const float* Wmix_vs2 = (const float*)d_in[15];

    float* out  = (float*)d_out;
    float* s_ws = (float*)d_ws;                        // [512][32][64] f32 = 4 MB
    float* v_ws = s_ws + (size_t)NB * NATOM * NE;      // [512][32][48] f32 = 3 MB

    dim3 grid(NB, 8), block(256);
    layer1_kernel<<<grid, block, 0, stream>>>(Z, geometry, mask, emb,
                                              Wr_ss1, Wmix_ss1, Wr_sv1, Wmix_sv1,
                                              s_ws, v_ws);
    layer2_kernel<<<grid, block, 0, stream>>>(geometry, mask,
                                              Wr_ss2, Wmix_ss2, Wr_sv2, Wmix_sv2,
                                              Wr_vv2, Wmix_vv2, Wr_vs2, Wmix_vs2,
                                              s_ws, v_ws, out);
}

// Round 6
// 204.541 us; speedup vs baseline: 1.5397x; 1.2103x over previous
//
#include <hip/hip_runtime.h>
#include <math.h>

#define NB 512
#define NATOM 32
#define NE 64
#define NK 32
#define NL1 16
#define NSG 80
#define CSTEP (5.0f / 31.0f)   // RMAX/(K-1)

// workspace byte offsets (after s_ws 4MB + v_ws 3MB)
#define PK1_OFF 7340032u           // [4 t][2 hl][2 ks][64 lane] * 16B = 16 KB
#define PK2_OFF (PK1_OFF + 16384u) // [5][2][2][64] * 16B = 20 KB
#define PM1_OFF (PK2_OFF + 20480u) // [16 c4][3 q][64 lane] * 16B = 48 KB
#define PM2_OFF (PM1_OFF + 49152u) // 48 KB
#define PMB_OFF (PM2_OFF + 49152u) // [4 c4][3 q][64 lane] * 16B = 12 KB

typedef __attribute__((ext_vector_type(8)))  short s8v;    // 8 bf16 (4 VGPR) MFMA operand
typedef __attribute__((ext_vector_type(16))) float f16v;   // 32x32 accumulator

__device__ __forceinline__ float sigm(float x) { return 1.0f / (1.0f + __expf(-x)); }

__device__ __forceinline__ short f2bf(float f) {
    unsigned u = __float_as_uint(f);
    unsigned r = (u + 0x7fffu + ((u >> 16) & 1u)) >> 16;
    return (short)r;
}
__device__ __forceinline__ float bf2f(short s) {
    return __uint_as_float(((unsigned)(unsigned short)s) << 16);
}

// ---------------- prep: pack B-fragments + mix tables ----------------
// items: [0,1024) pk1 | [1024,2304) pk2 | [2304,5376) pm1 | [5376,8448) pm2 | [8448,9216) pmB
__global__ __launch_bounds__(256) void prep_kernel(
    const float* __restrict__ Wr_ss1, const float* __restrict__ Wmix_ss1,
    const float* __restrict__ Wr_sv1, const float* __restrict__ Wmix_sv1,
    const float* __restrict__ Wr_ss2, const float* __restrict__ Wmix_ss2,
    const float* __restrict__ Wr_sv2, const float* __restrict__ Wmix_sv2,
    const float* __restrict__ Wr_vv2, const float* __restrict__ Wmix_vv2,
    const float* __restrict__ Wr_vs2, const float* __restrict__ Wmix_vs2,
    char* __restrict__ ws)
{
    const int i = blockIdx.x * 256 + threadIdx.x;
    if (i < 2304) {
        // B-fragment packs
        int j, nt; const float* Wss; const float* Wsv; unsigned* dst;
        if (i < 1024) { j = i;        dst = (unsigned*)(ws + PK1_OFF); Wss = Wr_ss1; Wsv = Wr_sv1; nt = j >> 8; }
        else          { j = i - 1024; dst = (unsigned*)(ws + PK2_OFF); Wss = Wr_ss2; Wsv = Wr_sv2; nt = j >> 8; }
        const int r    = j & 255;
        const int hl   = r >> 7;
        const int ks   = (r >> 6) & 1;
        const int lane = r & 63;
        const int l31  = lane & 31;
        const int hi   = lane >> 5;
        const float* src; int stride;
        if (nt < 2)      { src = Wss + nt * 32 + l31;       stride = 64; }
        else if (nt < 4) { src = Wsv + (nt - 2) * 32 + l31; stride = 64; }
        else             { src = (l31 < 16) ? (Wr_vv2 + l31) : (Wr_vs2 + (l31 - 16)); stride = 16; }
        unsigned u4[4] = {0, 0, 0, 0};
#pragma unroll
        for (int jj = 0; jj < 8; jj++) {
            int k = ks * 16 + hi * 8 + jj;
            float w = src[k * stride];
            short h = f2bf(w);
            short val = hl ? f2bf(w - bf2f(h)) : h;
            u4[jj >> 1] |= ((unsigned)(unsigned short)val) << (16 * (jj & 1));
        }
        *reinterpret_cast<uint4*>(dst + (size_t)j * 4) = make_uint4(u4[0], u4[1], u4[2], u4[3]);
    } else if (i < 9216) {
        // mix tables: pm[c4][q][lane] = float4 over u=0..3 (c = 4*c4+u)
        int j; const float* Wm_s; const float* Wm_v; float4* dst; 
        if (i < 5376)      { j = i - 2304; dst = (float4*)(ws + PM1_OFF); Wm_s = Wmix_ss1; Wm_v = Wmix_sv1; }
        else if (i < 8448) { j = i - 5376; dst = (float4*)(ws + PM2_OFF); Wm_s = Wmix_ss2; Wm_v = Wmix_sv2; }
        else               { j = i - 8448; dst = (float4*)(ws + PMB_OFF); Wm_s = Wmix_vs2; Wm_v = Wmix_vv2; }
        const int c4   = j / 192;
        const int q    = (j / 64) % 3;
        const int lane = j & 63;
        const int d    = lane & 15;
        float4 v;
#pragma unroll
        for (int u = 0; u < 4; u++) {
            int c = c4 * 4 + u;
            float w;
            if (q == 0)      w = Wm_s[c * NSG + lane];
            else if (q == 1) w = Wm_s[c * NSG + 64 + d];
            else             w = Wm_v[c * NL1 + d];
            (&v.x)[u] = w;
        }
        dst[j] = v;
    }
}

#define PKIDX(t, hl, ks) (((((t) * 2 + (hl)) * 2 + (ks)) << 6) + lane)

// ---------------- layer 1 ----------------
// grid (512, 8), block 256. wave w = atom a0+w. MFMA: C[n=32][c=128] = G_a[n][k=32] @ Wcat[k][c]
__global__ __launch_bounds__(256) void layer1_kernel(
    const int* __restrict__ Z, const float* __restrict__ geometry,
    const float* __restrict__ mask, const float* __restrict__ emb,
    const char* __restrict__ ws_ro,
    float* __restrict__ s_ws, float* __restrict__ v_ws)
{
    __shared__ float s1[NATOM][NE];                    // 8 KB
    __shared__ __align__(16) float rh4[4][NATOM][4];   // 2 KB {rhat.xyz, rad}
    __shared__ __align__(16) float epi_s[4][NE];       // 1 KB
    __shared__ __align__(16) float epi_h[4][3][NE];    // 3 KB
    __shared__ float geo[NATOM][3];
    __shared__ float ml[NATOM];
    __shared__ int   zl[NATOM];

    const s8v*    pk = (const s8v*)   (ws_ro + PK1_OFF);
    const float4* pm = (const float4*)(ws_ro + PM1_OFF);

    const int b    = blockIdx.x;
    const int a0   = blockIdx.y * 4;
    const int tid  = threadIdx.x;
    const int wave = tid >> 6;
    const int lane = tid & 63;
    const int l31  = lane & 31;
    const int hi   = lane >> 5;

    if (tid < 96)                 geo[tid / 3][tid % 3] = geometry[b * 96 + tid];
    if (tid >= 128 && tid < 160)  ml[tid - 128] = mask[b * NATOM + (tid - 128)];
    if (tid >= 192 && tid < 224)  zl[tid - 192] = Z[b * NATOM + (tid - 192)];
    __syncthreads();

    float msum = 0.f;
#pragma unroll
    for (int n = 0; n < NATOM; n++) msum += ml[n];
    const float scale = 1.0f / sqrtf(msum);

    for (int idx = tid; idx < NATOM * NE; idx += 256) {
        s1[idx >> 6][idx & 63] = emb[zl[idx >> 6] * NE + (idx & 63)] * scale;
    }
    for (int p = tid; p < 4 * NATOM; p += 256) {
        int ai = p >> 5, n = p & 31, a = a0 + ai;
        float dx = geo[n][0] - geo[a][0];
        float dy = geo[n][1] - geo[a][1];
        float dz = geo[n][2] - geo[a][2];
        float rad = sqrtf(dx * dx + dy * dy + dz * dz + 1e-12f);
        float inv = 1.0f / (rad + 1e-8f);
        rh4[ai][n][0] = dx * inv; rh4[ai][n][1] = dy * inv;
        rh4[ai][n][2] = dz * inv; rh4[ai][n][3] = rad;
    }
    __syncthreads();

    // ---- A fragments: G row n = l31 of this wave's atom, in-register ----
    const float rn  = rh4[wave][l31][3];
    const float mln = ml[l31];
    s8v Ah[2], Al[2];
#pragma unroll
    for (int ks = 0; ks < 2; ks++) {
#pragma unroll
        for (int j = 0; j < 8; j++) {
            float mu = (float)(ks * 16 + hi * 8 + j) * CSTEP;
            float dd = rn - mu;
            float g  = __expf(-10.0f * dd * dd) * mln;
            short h  = f2bf(g);
            Ah[ks][j] = h;
            Al[ks][j] = f2bf(g - bf2f(h));
        }
    }

    // ---- MFMA phases: pair p covers ss-tile p and sv-tile p+2 (B from packed table) ----
#pragma unroll
    for (int p = 0; p < 2; p++) {
        s8v bhs[2], bls[2], bhv[2], blv[2];
#pragma unroll
        for (int ks = 0; ks < 2; ks++) {
            bhs[ks] = pk[PKIDX(p,     0, ks)];
            bls[ks] = pk[PKIDX(p,     1, ks)];
            bhv[ks] = pk[PKIDX(p + 2, 0, ks)];
            blv[ks] = pk[PKIDX(p + 2, 1, ks)];
        }
        f16v accS = {};
        f16v accV = {};
#pragma unroll
        for (int ks = 0; ks < 2; ks++) {
            accS = __builtin_amdgcn_mfma_f32_32x32x16_bf16(Ah[ks], bhs[ks], accS, 0, 0, 0);
            accS = __builtin_amdgcn_mfma_f32_32x32x16_bf16(Al[ks], bhs[ks], accS, 0, 0, 0);
            accS = __builtin_amdgcn_mfma_f32_32x32x16_bf16(Ah[ks], bls[ks], accS, 0, 0, 0);
            accV = __builtin_amdgcn_mfma_f32_32x32x16_bf16(Ah[ks], bhv[ks], accV, 0, 0, 0);
            accV = __builtin_amdgcn_mfma_f32_32x32x16_bf16(Al[ks], bhv[ks], accV, 0, 0, 0);
            accV = __builtin_amdgcn_mfma_f32_32x32x16_bf16(Ah[ks], blv[ks], accV, 0, 0, 0);
        }
        const int c = p * 32 + l31;
        float ps = 0.f, g0 = 0.f, g1 = 0.f, g2 = 0.f;
#pragma unroll
        for (int r = 0; r < 16; r++) {
            int n = (r & 3) + 8 * (r >> 2) + 4 * hi;   // verified C/D row map (m74/m101)
            float sv = s1[n][c];
            ps = fmaf(accS[r], sv, ps);
            float t = accV[r] * sv;
            float4 rr = *reinterpret_cast<const float4*>(&rh4[wave][n][0]);
            g0 = fmaf(t, rr.x, g0);
            g1 = fmaf(t, rr.y, g1);
            g2 = fmaf(t, rr.z, g2);
        }
        ps += __shfl_xor(ps, 32);
        g0 += __shfl_xor(g0, 32);
        g1 += __shfl_xor(g1, 32);
        g2 += __shfl_xor(g2, 32);
        if (hi == 0) {
            epi_s[wave][c]    = ps;
            epi_h[wave][0][c] = g0;
            epi_h[wave][1][c] = g1;
            epi_h[wave][2][c] = g2;
        }
    }

    // ---- mix + activations via packed pm table ----
    const int d  = lane & 15;
    const int x  = lane >> 4;
    const int xe = (x > 2) ? 0 : x;
    float so = 0.f, so2 = 0.f, vo = 0.f;
    const float4* es4 = reinterpret_cast<const float4*>(&epi_s[wave][0]);
    const float4* eh4 = reinterpret_cast<const float4*>(&epi_h[wave][xe][0]);
#pragma unroll 4
    for (int c4 = 0; c4 < 16; c4++) {
        float4 w0 = pm[(c4 * 3 + 0) * 64 + lane];
        float4 w1 = pm[(c4 * 3 + 1) * 64 + lane];
        float4 w2 = pm[(c4 * 3 + 2) * 64 + lane];
        float4 sp = es4[c4];
        float4 hp = eh4[c4];
#pragma unroll
        for (int u = 0; u < 4; u++) {
            so  = fmaf((&sp.x)[u], (&w0.x)[u], so);
            so2 = fmaf((&sp.x)[u], (&w1.x)[u], so2);
            vo  = fmaf((&hp.x)[u], (&w2.x)[u], vo);
        }
    }
    const float mla = ml[a0 + wave];
    s_ws[(b * NATOM + a0 + wave) * NE + lane] = so * sigm(so) * mla;
    if (lane < 48) {
        v_ws[(b * NATOM + a0 + wave) * 48 + d * 3 + x] = vo * sigm(so2) * mla;
    }
}

// ---------------- layer 2 ----------------
__global__ __launch_bounds__(256) void layer2_kernel(
    const float* __restrict__ geometry, const float* __restrict__ mask,
    const char* __restrict__ ws_ro,
    const float* __restrict__ s_ws, const float* __restrict__ v_ws,
    float* __restrict__ out)
{
    __shared__ float s2[NATOM][NE];                    // 8 KB
    __shared__ float v2[NATOM][48];                    // 6 KB
    __shared__ __align__(16) float rh4[4][NATOM][4];   // 2 KB
    __shared__ float rv[4][NATOM][NL1];                // 8 KB
    __shared__ __align__(16) float epi_s[4][NE];       // 1 KB
    __shared__ __align__(16) float epi_h[4][3][NE];    // 3 KB
    __shared__ __align__(16) float epi_vv[4][3][NL1];  // 0.75 KB
    __shared__ __align__(16) float epi_vs[4][NL1];     // 0.25 KB
    __shared__ float geo[NATOM][3];
    __shared__ float ml[NATOM];

    const s8v*    pk  = (const s8v*)   (ws_ro + PK2_OFF);
    const float4* pm  = (const float4*)(ws_ro + PM2_OFF);
    const float4* pmB = (const float4*)(ws_ro + PMB_OFF);

    const int b    = blockIdx.x;
    const int a0   = blockIdx.y * 4;
    const int tid  = threadIdx.x;
    const int wave = tid >> 6;
    const int lane = tid & 63;
    const int l31  = lane & 31;
    const int hi   = lane >> 5;

    if (tid < 96)                 geo[tid / 3][tid % 3] = geometry[b * 96 + tid];
    if (tid >= 128 && tid < 160)  ml[tid - 128] = mask[b * NATOM + (tid - 128)];
    __syncthreads();

    float msum = 0.f;
#pragma unroll
    for (int n = 0; n < NATOM; n++) msum += ml[n];
    const float scale = 1.0f / sqrtf(msum);

    for (int idx = tid; idx < NATOM * NE; idx += 256) {
        s2[idx >> 6][idx & 63] = s_ws[b * (NATOM * NE) + idx] * scale;
    }
    for (int idx = tid; idx < NATOM * 48; idx += 256) {
        v2[idx / 48][idx % 48] = v_ws[b * (NATOM * 48) + idx] * scale;
    }
    for (int p = tid; p < 4 * NATOM; p += 256) {
        int ai = p >> 5, n = p & 31, a = a0 + ai;
        float dx = geo[n][0] - geo[a][0];
        float dy = geo[n][1] - geo[a][1];
        float dz = geo[n][2] - geo[a][2];
        float rad = sqrtf(dx * dx + dy * dy + dz * dz + 1e-12f);
        float inv = 1.0f / (rad + 1e-8f);
        rh4[ai][n][0] = dx * inv; rh4[ai][n][1] = dy * inv;
        rh4[ai][n][2] = dz * inv; rh4[ai][n][3] = rad;
    }
    __syncthreads();
    for (int idx = tid; idx < 4 * NATOM * NL1; idx += 256) {
        int ai = idx >> 9, n = (idx >> 4) & 31, c = idx & 15;
        rv[ai][n][c] = rh4[ai][n][0] * v2[n][c * 3 + 0]
                     + rh4[ai][n][1] * v2[n][c * 3 + 1]
                     + rh4[ai][n][2] * v2[n][c * 3 + 2];
    }
    __syncthreads();

    // ---- A fragments ----
    const float rn  = rh4[wave][l31][3];
    const float mln = ml[l31];
    s8v Ah[2], Al[2];
#pragma unroll
    for (int ks = 0; ks < 2; ks++) {
#pragma unroll
        for (int j = 0; j < 8; j++) {
            float mu = (float)(ks * 16 + hi * 8 + j) * CSTEP;
            float dd = rn - mu;
            float g  = __expf(-10.0f * dd * dd) * mln;
            short h  = f2bf(g);
            Ah[ks][j] = h;
            Al[ks][j] = f2bf(g - bf2f(h));
        }
    }

    // ---- pairs: (0,2) and (1,3) ----
#pragma unroll
    for (int p = 0; p < 2; p++) {
        s8v bhs[2], bls[2], bhv[2], blv[2];
#pragma unroll
        for (int ks = 0; ks < 2; ks++) {
            bhs[ks] = pk[PKIDX(p,     0, ks)];
            bls[ks] = pk[PKIDX(p,     1, ks)];
            bhv[ks] = pk[PKIDX(p + 2, 0, ks)];
            blv[ks] = pk[PKIDX(p + 2, 1, ks)];
        }
        f16v accS = {};
        f16v accV = {};
#pragma unroll
        for (int ks = 0; ks < 2; ks++) {
            accS = __builtin_amdgcn_mfma_f32_32x32x16_bf16(Ah[ks], bhs[ks], accS, 0, 0, 0);
            accS = __builtin_amdgcn_mfma_f32_32x32x16_bf16(Al[ks], bhs[ks], accS, 0, 0, 0);
            accS = __builtin_amdgcn_mfma_f32_32x32x16_bf16(Ah[ks], bls[ks], accS, 0, 0, 0);
            accV = __builtin_amdgcn_mfma_f32_32x32x16_bf16(Ah[ks], bhv[ks], accV, 0, 0, 0);
            accV = __builtin_amdgcn_mfma_f32_32x32x16_bf16(Al[ks], bhv[ks], accV, 0, 0, 0);
            accV = __builtin_amdgcn_mfma_f32_32x32x16_bf16(Ah[ks], blv[ks], accV, 0, 0, 0);
        }
        const int c = p * 32 + l31;
        float ps = 0.f, g0 = 0.f, g1 = 0.f, g2 = 0.f;
#pragma unroll
        for (int r = 0; r < 16; r++) {
            int n = (r & 3) + 8 * (r >> 2) + 4 * hi;
            float sv = s2[n][c];
            ps = fmaf(accS[r], sv, ps);
            float t = accV[r] * sv;
            float4 rr = *reinterpret_cast<const float4*>(&rh4[wave][n][0]);
            g0 = fmaf(t, rr.x, g0);
            g1 = fmaf(t, rr.y, g1);
            g2 = fmaf(t, rr.z, g2);
        }
        ps += __shfl_xor(ps, 32);
        g0 += __shfl_xor(g0, 32);
        g1 += __shfl_xor(g1, 32);
        g2 += __shfl_xor(g2, 32);
        if (hi == 0) {
            epi_s[wave][c]    = ps;
            epi_h[wave][0][c] = g0;
            epi_h[wave][1][c] = g1;
            epi_h[wave][2][c] = g2;
        }
    }

    // ---- tile 4: vv (l31<16) / vs (l31>=16) ----
    {
        s8v bh4[2], bl4[2];
#pragma unroll
        for (int ks = 0; ks < 2; ks++) {
            bh4[ks] = pk[PKIDX(4, 0, ks)];
            bl4[ks] = pk[PKIDX(4, 1, ks)];
        }
        f16v acc4 = {};
#pragma unroll
        for (int ks = 0; ks < 2; ks++) {
            acc4 = __builtin_amdgcn_mfma_f32_32x32x16_bf16(Ah[ks], bh4[ks], acc4, 0, 0, 0);
            acc4 = __builtin_amdgcn_mfma_f32_32x32x16_bf16(Al[ks], bh4[ks], acc4, 0, 0, 0);
            acc4 = __builtin_amdgcn_mfma_f32_32x32x16_bf16(Ah[ks], bl4[ks], acc4, 0, 0, 0);
        }
        const int c16 = l31 & 15;
        float hv0 = 0.f, hv1 = 0.f, hv2 = 0.f, svs = 0.f;
#pragma unroll
        for (int r = 0; r < 16; r++) {
            int n = (r & 3) + 8 * (r >> 2) + 4 * hi;
            if (l31 < 16) {
                hv0 = fmaf(acc4[r], v2[n][c16 * 3 + 0], hv0);
                hv1 = fmaf(acc4[r], v2[n][c16 * 3 + 1], hv1);
                hv2 = fmaf(acc4[r], v2[n][c16 * 3 + 2], hv2);
            } else {
                svs = fmaf(acc4[r], rv[wave][n][c16], svs);
            }
        }
        hv0 += __shfl_xor(hv0, 32);
        hv1 += __shfl_xor(hv1, 32);
        hv2 += __shfl_xor(hv2, 32);
        svs += __shfl_xor(svs, 32);
        if (hi == 0) {
            if (l31 < 16) {
                epi_vv[wave][0][c16] = hv0;
                epi_vv[wave][1][c16] = hv1;
                epi_vv[wave][2][c16] = hv2;
            } else {
                epi_vs[wave][c16] = svs;
            }
        }
    }

    // ---- mix + activations via packed tables ----
    const int d  = lane & 15;
    const int x  = lane >> 4;
    const int xe = (x > 2) ? 0 : x;
    float so = 0.f, so2 = 0.f, vo = 0.f;
    const float4* es4 = reinterpret_cast<const float4*>(&epi_s[wave][0]);
    const float4* eh4 = reinterpret_cast<const float4*>(&epi_h[wave][xe][0]);
#pragma unroll 4
    for (int c4 = 0; c4 < 16; c4++) {
        float4 w0 = pm[(c4 * 3 + 0) * 64 + lane];
        float4 w1 = pm[(c4 * 3 + 1) * 64 + lane];
        float4 w2 = pm[(c4 * 3 + 2) * 64 + lane];
        float4 sp = es4[c4];
        float4 hp = eh4[c4];
#pragma unroll
        for (int u = 0; u < 4; u++) {
            so  = fmaf((&sp.x)[u], (&w0.x)[u], so);
            so2 = fmaf((&sp.x)[u], (&w1.x)[u], so2);
            vo  = fmaf((&hp.x)[u], (&w2.x)[u], vo);
        }
    }
    const float4* evs4 = reinterpret_cast<const float4*>(&epi_vs[wave][0]);
    const float4* evv4 = reinterpret_cast<const float4*>(&epi_vv[wave][xe][0]);
#pragma unroll
    for (int c4 = 0; c4 < 4; c4++) {
        float4 w0 = pmB[(c4 * 3 + 0) * 64 + lane];
        float4 w1 = pmB[(c4 * 3 + 1) * 64 + lane];
        float4 w2 = pmB[(c4 * 3 + 2) * 64 + lane];
        float4 vs = evs4[c4];
        float4 vv = evv4[c4];
#pragma unroll
        for (int u = 0; u < 4; u++) {
            so  = fmaf((&vs.x)[u], (&w0.x)[u], so);
            so2 = fmaf((&vs.x)[u], (&w1.x)[u], so2);
            vo  = fmaf((&vv.x)[u], (&w2.x)[u], vo);
        }
    }
    const float mla = ml[a0 + wave];
    float* orow = out + (b * NATOM + a0 + wave) * (NE + 3 * NL1);
    orow[lane] = so * sigm(so) * mla;
    if (lane < 48) {
        orow[64 + d * 3 + x] = vo * sigm(so2) * mla;
    }
}

extern "C" void kernel_launch(void* const* d_in, const int* in_sizes, int n_in,
                              void* d_out, int out_size, void* d_ws, size_t ws_size,
                              hipStream_t stream)
{
    const int*   Z        = (const int*)  d_in[0];
    const float* geometry = (const float*)d_in[1];
    const float* mask     = (const float*)d_in[2];
    const float* emb      = (const float*)d_in[3];
    const float* Wr_ss1   = (const float*)d_in[4];
    const float* Wmix_ss1 = (const float*)d_in[5];
    const float* Wr_sv1   = (const float*)d_in[6];
    const float* Wmix_sv1 = (const float*)d_in[7];
    const float* Wr_ss2   = (const float*)d_in[8];
    const float* Wmix_ss2 = (const float*)d_in[9];
    const float* Wr_sv2   = (const float*)d_in[10];
    const float* Wmix_sv2 = (const float*)d_in[11];
    const float* Wr_vv2   = (const float*)d_in[12];
    const float* Wmix_vv2 = (const float*)d_in[13];
    const float* Wr_vs2   = (const float*)d_in[14];
    const float* Wmix_vs2 = (const float*)d_in[15];

    float* out  = (float*)d_out;
    char*  ws   = (char*)d_ws;
    float* s_ws = (float*)d_ws;                        // [512][32][64] f32 = 4 MB
    float* v_ws = s_ws + (size_t)NB * NATOM * NE;      // [512][32][48] f32 = 3 MB

    prep_kernel<<<36, 256, 0, stream>>>(Wr_ss1, Wmix_ss1, Wr_sv1, Wmix_sv1,
                                        Wr_ss2, Wmix_ss2, Wr_sv2, Wmix_sv2,
                                        Wr_vv2, Wmix_vv2, Wr_vs2, Wmix_vs2, ws);

    dim3 grid(NB, 8), block(256);
    layer1_kernel<<<grid, block, 0, stream>>>(Z, geometry, mask, emb,
                                              (const char*)d_ws, s_ws, v_ws);
    layer2_kernel<<<grid, block, 0, stream>>>(geometry, mask,
                                              (const char*)d_ws, s_ws, v_ws, out);
}